// Round 6
// baseline (76.410 us; speedup 1.0000x reference)
//
#include <hip/hip_runtime.h>
#include <stdint.h>

#define DD 512
#define NP 1024
#define NB 16

typedef __attribute__((ext_vector_type(8))) __bf16 bf16x8;
typedef __attribute__((ext_vector_type(4))) float f32x4;

// ws layout: khw f32 [16][64][1024] (4MB) | tbl bf16 [2][64][256] swizzled (64KB) | G f32 [64][64]

__device__ __forceinline__ bf16x8 cvt8(const float4& a, const float4& b) {
    bf16x8 r;
    r[0]=(__bf16)a.x; r[1]=(__bf16)a.y; r[2]=(__bf16)a.z; r[3]=(__bf16)a.w;
    r[4]=(__bf16)b.x; r[5]=(__bf16)b.y; r[6]=(__bf16)b.z; r[7]=(__bf16)b.w;
    return r;
}

__device__ __forceinline__ void gload_lds16(const void* g, void* l) {
    __builtin_amdgcn_global_load_lds(
        (const __attribute__((address_space(1))) unsigned int*)g,
        (__attribute__((address_space(3))) unsigned int*)l,
        16, 0, 0);
}

// EHW row r: r<32 -> embed[r*32][col..]; r>=32 -> embed[r-32][col..] - embed[0][col..]
__device__ __forceinline__ bf16x8 ehw_row(const float* __restrict__ embed, int r,
                                          int col, const float4& z0, const float4& z1) {
    int srcrow = (r < 32) ? (r << 5) : (r - 32);
    const float* sp = embed + (size_t)srcrow * DD + col;
    float4 a = *(const float4*)sp;
    float4 b = *(const float4*)(sp + 4);
    if (r >= 32) {
        a.x -= z0.x; a.y -= z0.y; a.z -= z0.z; a.w -= z0.w;
        b.x -= z1.x; b.y -= z1.y; b.z -= z1.z; b.w -= z1.w;
    }
    return cvt8(a, b);
}

// ---------- prep: blocks 0..15 build pre-swizzled bf16 table; block 16 builds G ----------
__global__ __launch_bounds__(256) void prep(
    const float* __restrict__ embed, unsigned short* __restrict__ tbl,
    float* __restrict__ G)
{
    const int tid = threadIdx.x;
    if (blockIdx.x < 16) {
        int g = blockIdx.x * 256 + tid;        // 0..4095
        int row = g >> 6;                      // 0..63
        int c8  = (g & 63) * 8;                // 0..504
        float4 z0 = *(const float4*)(embed + c8);
        float4 z1 = *(const float4*)(embed + c8 + 4);
        bf16x8 r = ehw_row(embed, row, c8, z0, z1);
        int h  = c8 >> 8;
        int cl = c8 & 255;
        int byte = (cl * 2) ^ ((row & 7) << 4);          // bake LDS swizzle
        *(bf16x8*)((char*)tbl + h * 32768 + row * 512 + byte) = r;
    } else {
        // G = EHW . EHW^T (64x64); symmetric, layout-safe
        const int lane = tid & 63, wid = tid >> 6;
        const int lr = lane & 15, kq = (lane >> 4) * 8;
        f32x4 acc[4];
        #pragma unroll
        for (int n = 0; n < 4; ++n) acc[n] = (f32x4)0.0f;
        for (int ks = 0; ks < 16; ++ks) {
            int col = ks * 32 + kq;
            float4 z0 = *(const float4*)(embed + col);
            float4 z1 = *(const float4*)(embed + col + 4);
            bf16x8 af = ehw_row(embed, wid * 16 + lr, col, z0, z1);
            #pragma unroll
            for (int n = 0; n < 4; ++n) {
                bf16x8 bf = ehw_row(embed, n * 16 + lr, col, z0, z1);
                acc[n] = __builtin_amdgcn_mfma_f32_16x16x32_bf16(af, bf, acc[n], 0, 0, 0);
            }
        }
        int row0 = wid * 16 + (lane >> 4) * 4;
        #pragma unroll
        for (int n = 0; n < 4; ++n)
            #pragma unroll
            for (int i = 0; i < 4; ++i)
                G[(size_t)(row0 + i) * 64 + n * 16 + lr] = acc[n][i];
    }
}

// ---------- kgemm: khw[b][m][Q] = EHW[m,:] . k[b,Q,:]  (full K=512) ----------
__global__ __launch_bounds__(256) void kgemm(
    const float* __restrict__ kin, const unsigned short* __restrict__ tbl,
    float* __restrict__ khw)
{
    __shared__ __align__(16) unsigned short T[64 * 512];   // 64KB, [2][64][256] halves

    const int tid = threadIdx.x, lane = tid & 63, wid = tid >> 6;
    const int lr = lane & 15, kq = (lane >> 4) * 8;

    #pragma unroll
    for (int c = 0; c < 16; ++c) {
        int off = wid * 16384 + c * 1024;
        gload_lds16((const char*)tbl + off + lane * 16, (char*)T + off);
    }

    const int grow = blockIdx.x * 64 + wid * 16 + lr;      // 0..16383
    const float* srcA = kin + (size_t)grow * DD + kq;

    f32x4 acc[4];
    #pragma unroll
    for (int n = 0; n < 4; ++n) acc[n] = (f32x4)0.0f;
    __syncthreads();

    #pragma unroll 8
    for (int ks = 0; ks < 16; ++ks) {
        float4 a0 = *(const float4*)(srcA + ks * 32);
        float4 a1 = *(const float4*)(srcA + ks * 32 + 4);
        bf16x8 sf = cvt8(a0, a1);
        const char* Th = (const char*)T + (ks >> 3) * 32768;
        int kb = ((ks & 7) * 32 + kq) * 2;
        bf16x8 ef[4];
        #pragma unroll
        for (int n = 0; n < 4; ++n) {
            int row = n * 16 + lr;
            ef[n] = *(const bf16x8*)(Th + row * 512 + (kb ^ ((row & 7) << 4)));
        }
        #pragma unroll
        for (int n = 0; n < 4; ++n)
            acc[n] = __builtin_amdgcn_mfma_f32_16x16x32_bf16(ef[n], sf, acc[n], 0, 0, 0);
    }

    int b = grow >> 10, Q = grow & 1023;
    float* o = khw + (size_t)b * 65536 + Q;
    int m0 = (lane >> 4) * 4;
    #pragma unroll
    for (int n = 0; n < 4; ++n)
        #pragma unroll
        for (int i = 0; i < 4; ++i)
            o[(size_t)(n * 16 + m0 + i) * 1024] = acc[n][i];
}

// ---------- asm2: fused q-projection + Gram fold + output assembly ----------
// out[b][P=(i,j)][Q=(kq,lq)] = kh[i][Q] + kw[j][Q] + d1[j][kq] + d2[j][lq]
__global__ __launch_bounds__(256) void asm2(
    const float* __restrict__ q, const float* __restrict__ khw,
    const unsigned short* __restrict__ tbl, const float* __restrict__ G,
    float* __restrict__ out)
{
    __shared__ __align__(16) unsigned short T[64 * 512];   // 64KB
    __shared__ __align__(16) float kh[NP];                 // 4KB
    __shared__ __align__(16) float dq[16][64];             // 4KB
    __shared__ __align__(16) float d1[16][32];             // 2KB
    __shared__ __align__(16) float d2[16][32];             // 2KB

    const int tid = threadIdx.x, lane = tid & 63, wid = tid >> 6;
    const int lr = lane & 15, kq = (lane >> 4) * 8;
    const int b  = blockIdx.x >> 6;
    const int i  = (blockIdx.x >> 1) & 31;
    const int jh = blockIdx.x & 1;

    // DMA table + kh row (issued together, drained at the barrier)
    #pragma unroll
    for (int c = 0; c < 16; ++c) {
        int off = wid * 16384 + c * 1024;
        gload_lds16((const char*)tbl + off + lane * 16, (char*)T + off);
    }
    gload_lds16((const char*)(khw + (size_t)b * 65536 + (size_t)i * 1024)
                    + wid * 1024 + lane * 16,
                (char*)kh + wid * 1024);

    // q-side projection: wave w covers table rows w*16..w*16+15, full K
    const int Pbase = i * 32 + jh * 16;
    const float* qs = q + ((size_t)b * NP + Pbase + lr) * DD + kq;

    f32x4 acc = (f32x4)0.0f;
    __syncthreads();

    #pragma unroll 4
    for (int ks = 0; ks < 16; ++ks) {
        float4 a0 = *(const float4*)(qs + ks * 32);
        float4 a1 = *(const float4*)(qs + ks * 32 + 4);
        bf16x8 sf = cvt8(a0, a1);
        const int row = wid * 16 + lr;
        const char* Th = (const char*)T + (ks >> 3) * 32768;
        int kb = ((ks & 7) * 32 + kq) * 2;
        bf16x8 ef = *(const bf16x8*)(Th + row * 512 + (kb ^ ((row & 7) << 4)));
        acc = __builtin_amdgcn_mfma_f32_16x16x32_bf16(sf, ef, acc, 0, 0, 0);
    }
    // C/D: col=lane&15 -> table row m; row=(lane>>4)*4+r -> q row jj
    {
        int jj0 = (lane >> 4) * 4;
        #pragma unroll
        for (int r = 0; r < 4; ++r) dq[jj0 + r][wid * 16 + lr] = acc[r];
    }
    __syncthreads();

    // fold Gram terms:
    // d1[jj][c] = dq[jj][c]    + G[i][c]    + G[32+j][c]      (c = kq index)
    // d2[jj][c] = dq[jj][32+c] + G[i][32+c] + G[32+j][32+c]   (c = lq index)
    {
        int jj = tid >> 4, c = tid & 15;
        int j  = jh * 16 + jj;
        const float* Gi = G + (size_t)i * 64;
        const float* Gj = G + (size_t)(32 + j) * 64;
        d1[jj][c]      = dq[jj][c]      + Gi[c]      + Gj[c];
        d1[jj][c + 16] = dq[jj][c + 16] + Gi[c + 16] + Gj[c + 16];
        d2[jj][c]      = dq[jj][32 + c] + Gi[32 + c] + Gj[32 + c];
        d2[jj][c + 16] = dq[jj][48 + c] + Gi[48 + c] + Gj[48 + c];
    }
    __syncthreads();

    const int Q0 = tid * 4;
    const int kidx = Q0 >> 5;
    const int lidx = Q0 & 31;
    const float4 khv = *(const float4*)&kh[Q0];

    float* orow = out + ((size_t)b * NP + Pbase) * NP + Q0;
    const float* kwb = khw + (size_t)b * 65536 + (size_t)(32 + jh * 16) * 1024 + Q0;

    #pragma unroll 4
    for (int jj = 0; jj < 16; ++jj) {
        float4 kw = *(const float4*)(kwb + (size_t)jj * 1024);
        float  s1 = d1[jj][kidx];
        float4 s2 = *(const float4*)&d2[jj][lidx];
        float4 v;
        v.x = khv.x + kw.x + s1 + s2.x;
        v.y = khv.y + kw.y + s1 + s2.y;
        v.z = khv.z + kw.z + s1 + s2.z;
        v.w = khv.w + kw.w + s1 + s2.w;
        *(float4*)(orow + (size_t)jj * NP) = v;
    }
}

extern "C" void kernel_launch(void* const* d_in, const int* in_sizes, int n_in,
                              void* d_out, int out_size, void* d_ws, size_t ws_size,
                              hipStream_t stream) {
    const float* q = (const float*)d_in[0];
    const float* k = (const float*)d_in[1];
    const float* e = (const float*)d_in[2];
    float* out = (float*)d_out;

    float* khw = (float*)d_ws;                                   // 4 MB
    unsigned short* tbl = (unsigned short*)(khw + (size_t)NB * 64 * NP);  // 64 KB
    float* G = (float*)((char*)tbl + 65536);                     // 16 KB

    hipLaunchKernelGGL(prep,  dim3(17),   dim3(256), 0, stream, e, tbl, G);
    hipLaunchKernelGGL(kgemm, dim3(256),  dim3(256), 0, stream, k, tbl, khw);
    hipLaunchKernelGGL(asm2,  dim3(1024), dim3(256), 0, stream, q, khw, tbl, G, out);
}

// Round 8
// 52.815 us; speedup vs baseline: 1.4467x; 1.4467x over previous
//
#include <hip/hip_runtime.h>
#include <stdint.h>

#define DD 512
#define NP 1024
#define NB 16

typedef __attribute__((ext_vector_type(8))) __bf16 bf16x8;
typedef __attribute__((ext_vector_type(4))) float f32x4;

// ws layout (floats): qhw [16384][64] (4MB) | khw [16][64][1024] (4MB)
//                     | tbl bf16 [2][64][256] pre-swizzled (64KB) | G f32 [64][64]

__device__ __forceinline__ bf16x8 cvt8(const float4& a, const float4& b) {
    bf16x8 r;
    r[0]=(__bf16)a.x; r[1]=(__bf16)a.y; r[2]=(__bf16)a.z; r[3]=(__bf16)a.w;
    r[4]=(__bf16)b.x; r[5]=(__bf16)b.y; r[6]=(__bf16)b.z; r[7]=(__bf16)b.w;
    return r;
}

__device__ __forceinline__ void gload_lds16(const void* g, void* l) {
    __builtin_amdgcn_global_load_lds(
        (const __attribute__((address_space(1))) unsigned int*)g,
        (__attribute__((address_space(3))) unsigned int*)l,
        16, 0, 0);
}

// EHW row r: r<32 -> embed[r*32][col..]; r>=32 -> embed[r-32][col..] - embed[0][col..]
__device__ __forceinline__ bf16x8 ehw_row(const float* __restrict__ embed, int r,
                                          int col, const float4& z0, const float4& z1) {
    int srcrow = (r < 32) ? (r << 5) : (r - 32);
    const float* sp = embed + (size_t)srcrow * DD + col;
    float4 a = *(const float4*)sp;
    float4 b = *(const float4*)(sp + 4);
    if (r >= 32) {
        a.x -= z0.x; a.y -= z0.y; a.z -= z0.z; a.w -= z0.w;
        b.x -= z1.x; b.y -= z1.y; b.z -= z1.z; b.w -= z1.w;
    }
    return cvt8(a, b);
}

// ---------- prep: blocks 0..15 build pre-swizzled bf16 table; block 16 builds G ----
__global__ __launch_bounds__(256) void prep(
    const float* __restrict__ embed, unsigned short* __restrict__ tbl,
    float* __restrict__ G)
{
    const int tid = threadIdx.x;
    if (blockIdx.x < 16) {
        int g = blockIdx.x * 256 + tid;        // 0..4095
        int row = g >> 6;                      // 0..63
        int c8  = (g & 63) * 8;                // 0..504
        float4 z0 = *(const float4*)(embed + c8);
        float4 z1 = *(const float4*)(embed + c8 + 4);
        bf16x8 r = ehw_row(embed, row, c8, z0, z1);
        int h  = c8 >> 8;
        int cl = c8 & 255;
        int byte = (cl * 2) ^ ((row & 7) << 4);          // bake LDS swizzle
        *(bf16x8*)((char*)tbl + h * 32768 + row * 512 + byte) = r;
    } else {
        // G = EHW . EHW^T (64x64)
        const int lane = tid & 63, wid = tid >> 6;
        const int lr = lane & 15, kq = (lane >> 4) * 8;
        f32x4 acc[4];
        #pragma unroll
        for (int n = 0; n < 4; ++n) acc[n] = (f32x4)0.0f;
        for (int ks = 0; ks < 16; ++ks) {
            int col = ks * 32 + kq;
            float4 z0 = *(const float4*)(embed + col);
            float4 z1 = *(const float4*)(embed + col + 4);
            bf16x8 af = ehw_row(embed, wid * 16 + lr, col, z0, z1);
            #pragma unroll
            for (int n = 0; n < 4; ++n) {
                bf16x8 bf = ehw_row(embed, n * 16 + lr, col, z0, z1);
                acc[n] = __builtin_amdgcn_mfma_f32_16x16x32_bf16(af, bf, acc[n], 0, 0, 0);
            }
        }
        int row0 = wid * 16 + (lane >> 4) * 4;
        #pragma unroll
        for (int n = 0; n < 4; ++n)
            #pragma unroll
            for (int i = 0; i < 4; ++i)
                G[(size_t)(row0 + i) * 64 + n * 16 + lr] = acc[n][i];
    }
}

// ---------- rank_gemm: both thin GEMMs, DMA-staged table, full K=512 ----------
// blocks 0..255:  qhw[P][m]    = q[P,:]·EHW[m,:]       (P = global row, 64/block)
// blocks 256..511: khw[b][m][Q] = EHW[m,:]·k[b,Q,:]
__global__ __launch_bounds__(256) void rank_gemm(
    const float* __restrict__ q, const float* __restrict__ kin,
    const unsigned short* __restrict__ tbl,
    float* __restrict__ qhw, float* __restrict__ khw)
{
    __shared__ __align__(16) unsigned short T[64 * 512];   // 64 KB pre-swizzled

    const int tid = threadIdx.x, lane = tid & 63, wid = tid >> 6;
    const int lr = lane & 15, kq = (lane >> 4) * 8;
    const int gsel = blockIdx.x >> 8;
    const int tile = blockIdx.x & 255;

    #pragma unroll
    for (int c = 0; c < 16; ++c) {
        int off = wid * 16384 + c * 1024;
        gload_lds16((const char*)tbl + off + lane * 16, (char*)T + off);
    }

    const int grow = tile * 64 + wid * 16 + lr;            // 0..16383
    const float* srcA = (gsel ? kin : q) + (size_t)grow * DD + kq;

    f32x4 acc[4];
    #pragma unroll
    for (int n = 0; n < 4; ++n) acc[n] = (f32x4)0.0f;
    __syncthreads();

    #pragma unroll 8
    for (int ks = 0; ks < 16; ++ks) {
        float4 a0 = *(const float4*)(srcA + ks * 32);
        float4 a1 = *(const float4*)(srcA + ks * 32 + 4);
        bf16x8 sf = cvt8(a0, a1);
        const char* Th = (const char*)T + (ks >> 3) * 32768;
        int kb = ((ks & 7) * 32 + kq) * 2;
        bf16x8 ef[4];
        #pragma unroll
        for (int n = 0; n < 4; ++n) {
            int row = n * 16 + lr;
            ef[n] = *(const bf16x8*)(Th + row * 512 + (kb ^ ((row & 7) << 4)));
        }
        if (!gsel) {
            #pragma unroll
            for (int n = 0; n < 4; ++n)
                acc[n] = __builtin_amdgcn_mfma_f32_16x16x32_bf16(sf, ef[n], acc[n], 0, 0, 0);
        } else {
            #pragma unroll
            for (int n = 0; n < 4; ++n)
                acc[n] = __builtin_amdgcn_mfma_f32_16x16x32_bf16(ef[n], sf, acc[n], 0, 0, 0);
        }
    }

    if (!gsel) {
        // C row -> streamed P, C col -> table m
        float* o = qhw + (size_t)(tile * 64 + wid * 16 + (lane >> 4) * 4) * 64 + lr;
        #pragma unroll
        for (int n = 0; n < 4; ++n)
            #pragma unroll
            for (int i = 0; i < 4; ++i)
                o[(size_t)i * 64 + n * 16] = acc[n][i];
    } else {
        // C row -> table m, C col -> streamed Q
        int b = grow >> 10, Q = grow & 1023;
        float* o = khw + (size_t)b * 65536 + Q;
        int m0 = (lane >> 4) * 4;
        #pragma unroll
        for (int n = 0; n < 4; ++n)
            #pragma unroll
            for (int i = 0; i < 4; ++i)
                o[(size_t)(n * 16 + m0 + i) * 1024] = acc[n][i];
    }
}

// ---------- assemble: minimal writer ----------
// out[b][P=(i,j)][Q=(kq,lq)] = kh[i][Q] + kw[j][Q] + d1[jj][kq] + d2[jj][lq]
// d1[jj][c] = qhw[P][c]    + G[i][c]    + G[32+j][c]
// d2[jj][c] = qhw[P][32+c] + G[i][32+c] + G[32+j][32+c]
__global__ __launch_bounds__(256) void assemble(
    const float* __restrict__ qhw, const float* __restrict__ khw,
    const float* __restrict__ G, float* __restrict__ out)
{
    __shared__ __align__(16) float kh[NP];     // 4 KB
    __shared__ __align__(16) float d1[16][32];
    __shared__ __align__(16) float d2[16][32];

    const int tid = threadIdx.x, wid = tid >> 6, lane = tid & 63;
    const int b  = blockIdx.x >> 6;
    const int i  = (blockIdx.x >> 1) & 31;
    const int jh = blockIdx.x & 1;

    // kh row via DMA (1 KB per wave)
    gload_lds16((const char*)(khw + (size_t)b * 65536 + (size_t)i * 1024)
                    + wid * 1024 + lane * 16,
                (char*)kh + wid * 1024);

    // Gram + qhw fold (one pass, tid-parallel)
    {
        int jj = tid >> 4, c = tid & 15;
        int j  = jh * 16 + jj;
        size_t Prow = (size_t)b * NP + i * 32 + j;
        const float* qA = qhw + Prow * 64;
        const float* Gi = G + (size_t)i * 64;
        const float* Gj = G + (size_t)(32 + j) * 64;
        d1[jj][c]      = qA[c]      + Gi[c]      + Gj[c];
        d1[jj][c + 16] = qA[c + 16] + Gi[c + 16] + Gj[c + 16];
        d2[jj][c]      = qA[32 + c] + Gi[32 + c] + Gj[32 + c];
        d2[jj][c + 16] = qA[48 + c] + Gi[48 + c] + Gj[48 + c];
    }
    __syncthreads();

    const int Q0 = tid * 4;
    const int kidx = Q0 >> 5;
    const int lidx = Q0 & 31;
    const float4 khv = *(const float4*)&kh[Q0];

    float* orow = out + ((size_t)b * NP + i * 32 + jh * 16) * NP + Q0;
    const float* kwb = khw + (size_t)b * 65536 + (size_t)(32 + jh * 16) * 1024 + Q0;

    #pragma unroll 4
    for (int jj = 0; jj < 16; ++jj) {
        float4 kw = *(const float4*)(kwb + (size_t)jj * 1024);
        float  s1 = d1[jj][kidx];
        float4 s2 = *(const float4*)&d2[jj][lidx];
        f32x4 v;
        v.x = khv.x + kw.x + s1 + s2.x;
        v.y = khv.y + kw.y + s1 + s2.y;
        v.z = khv.z + kw.z + s1 + s2.z;
        v.w = khv.w + kw.w + s1 + s2.w;
        __builtin_nontemporal_store(v, (f32x4*)(orow + (size_t)jj * NP));
    }
}

extern "C" void kernel_launch(void* const* d_in, const int* in_sizes, int n_in,
                              void* d_out, int out_size, void* d_ws, size_t ws_size,
                              hipStream_t stream) {
    const float* q = (const float*)d_in[0];
    const float* k = (const float*)d_in[1];
    const float* e = (const float*)d_in[2];
    float* out = (float*)d_out;

    float* qhw = (float*)d_ws;                                    // 4 MB
    float* khw = qhw + (size_t)NB * NP * 64;                      // 4 MB
    unsigned short* tbl = (unsigned short*)(khw + (size_t)NB * 64 * NP); // 64 KB
    float* G = (float*)((char*)tbl + 65536);                      // 16 KB

    hipLaunchKernelGGL(prep,      dim3(17),   dim3(256), 0, stream, e, tbl, G);
    hipLaunchKernelGGL(rank_gemm, dim3(512),  dim3(256), 0, stream, q, k, tbl, qhw, khw);
    hipLaunchKernelGGL(assemble,  dim3(1024), dim3(256), 0, stream, qhw, khw, G, out);
}